// Round 11
// baseline (402.940 us; speedup 1.0000x reference)
//
#include <hip/hip_runtime.h>
#include <stdint.h>

typedef _Float16 half8 __attribute__((ext_vector_type(8)));
typedef float f32x4 __attribute__((ext_vector_type(4)));

typedef const __attribute__((address_space(1))) void* gptr_t;
typedef __attribute__((address_space(3))) void* lptr_t;
static __device__ __forceinline__ void gll16(const void* g, void* l) {
  __builtin_amdgcn_global_load_lds((gptr_t)(unsigned long long)g,
                                   (lptr_t)(unsigned int)(unsigned long long)l,
                                   16, 0, 0);
}

// ---- k_pb: B2 = f16(M @ W2 + nn2_b) in j-chunk layout (r9-verified) via r10's 1KB gll16 pipeline.
// grid (38,4): bx<36 workers (1024 cols, full K); bx==36 {y0: cheb+z0, y1: CSR+esrc/eatt}; bx==37: root(y=l).
// B2 element (j,o), j=c*192+i (c<5) or 960+k: halfs ((j>>3)*192+o)*8 + (j&7), per-layer stride 221184.
__global__ __launch_bounds__(256)
void k_pb(const float* __restrict__ nn2_w, const float* __restrict__ nn2_b,
          const float* __restrict__ eenc_w, const float* __restrict__ eenc_b,
          const float* __restrict__ nn1_w, const float* __restrict__ nn1_b,
          const float* __restrict__ root_w, _Float16* __restrict__ Btl,
          const float* __restrict__ x, const int* __restrict__ ei,
          const float* __restrict__ eattr, const float* __restrict__ cheb_w,
          const float* __restrict__ cheb_b, _Float16* __restrict__ z0,
          int* __restrict__ rowptr, int* __restrict__ esrc, float4* __restrict__ eatt) {
  __shared__ __align__(16) float smem[33728];  // workers: 4w x 8buf x 4KB + M[960]; riders reuse
  int t = threadIdx.x;
  if (blockIdx.x >= 36) {
    if (blockIdx.x == 36) {
      if (blockIdx.y == 0) {
        // ---- Chebyshev chain fully in LDS: TxL[5][4096] + yv[4096] (deg aliases yv) ----
        float* TxL = smem;            // 5*4096
        float* yv = smem + 20480;     // 4096
        float* deg = yv;
        for (int i = t; i < 1024; i += 256) deg[i] = 0.f;
        __syncthreads();
        for (int e = t; e < 2048; e += 256) atomicAdd(&deg[ei[e]], 1.f);
        __syncthreads();
        float wn[8];
#pragma unroll
        for (int i = 0; i < 8; ++i) {
          int e = t + 256 * i;
          int s = ei[e], d = ei[2048 + e];
          float ds = deg[s], dd = deg[d];
          float a = ds > 0.f ? 1.f / sqrtf(fmaxf(ds, 1.f)) : 0.f;
          float bb = dd > 0.f ? 1.f / sqrtf(fmaxf(dd, 1.f)) : 0.f;
          wn[i] = -a * bb;
        }
        __syncthreads();
        for (int q = 0; q < 4; ++q) {
          int i = t + 256 * q;
          ((float4*)TxL)[i] = ((const float4*)x)[i];
        }
        __syncthreads();
        for (int rec = 0; rec < 4; ++rec) {
          float* cur = TxL + rec * 4096;
          float* nxt = TxL + (rec + 1) * 4096;
          float* prv = TxL + (rec - 1) * 4096;  // only read when rec>0
          for (int i = t; i < 4096; i += 256) yv[i] = 0.f;
          __syncthreads();
#pragma unroll
          for (int i = 0; i < 8; ++i) {
            int e = t + 256 * i;
            int s = ei[e], d = ei[2048 + e];
            float wv = wn[i];
#pragma unroll
            for (int c = 0; c < 4; ++c) atomicAdd(&yv[d * 4 + c], wv * cur[s * 4 + c]);
          }
          __syncthreads();
          float a = rec ? 2.f : 1.f;
          for (int q = 0; q < 4; ++q) {
            int i = t + 256 * q;
            float4 y4 = ((float4*)yv)[i];
            float4 p4 = rec ? ((float4*)prv)[i] : make_float4(0.f, 0.f, 0.f, 0.f);
            float4 n4;
            n4.x = a * y4.x - p4.x; n4.y = a * y4.y - p4.y;
            n4.z = a * y4.z - p4.z; n4.w = a * y4.w - p4.w;
            ((float4*)nxt)[i] = n4;
          }
          __syncthreads();
        }
        // ---- z0[n*192+o] row-major f16; thread t<192 owns col o=t, cheb_w in regs ----
        if (t < 192) {
          float w20[20], cb;
#pragma unroll
          for (int kc = 0; kc < 20; ++kc) w20[kc] = cheb_w[kc * 192 + t];
          cb = cheb_b[t];
          for (int n = 0; n < 1024; ++n) {
            float acc = cb;
#pragma unroll
            for (int k = 0; k < 5; ++k)
#pragma unroll
              for (int c = 0; c < 4; ++c)
                acc += TxL[k * 4096 + n * 4 + c] * w20[k * 4 + c];
            z0[(size_t)n * 192 + t] = (_Float16)acc;
          }
        }
      } else if (blockIdx.y == 1) {
        // ---- CSR by dst: rowptr[1025] + CSR-ordered esrc/eatt ----
        int* cnt = (int*)smem;
        int* rp  = (int*)smem + 1024;
        int* wtot = (int*)smem + 2048;
        int lane = t & 63, wv = t >> 6;
        for (int i = t; i < 1024; i += 256) cnt[i] = 0;
        __syncthreads();
        for (int e = t; e < 2048; e += 256) atomicAdd(&cnt[ei[2048 + e]], 1);
        __syncthreads();
        int c0 = cnt[t * 4], c1 = cnt[t * 4 + 1], c2 = cnt[t * 4 + 2], c3 = cnt[t * 4 + 3];
        int s = c0 + c1 + c2 + c3;
        int inc = s;
#pragma unroll
        for (int off = 1; off < 64; off <<= 1) {
          int u = __shfl_up(inc, off);
          if (lane >= off) inc += u;
        }
        if (lane == 63) wtot[wv] = inc;
        __syncthreads();
        int woff = 0;
#pragma unroll
        for (int j = 0; j < 4; ++j) if (j < wv) woff += wtot[j];
        int excl = woff + inc - s;
        int4 r4; r4.x = excl; r4.y = excl + c0; r4.z = excl + c0 + c1; r4.w = excl + c0 + c1 + c2;
        *(int4*)(rowptr + t * 4) = r4;
        if (t == 0) rowptr[1024] = 2048;
        rp[t * 4] = r4.x; rp[t * 4 + 1] = r4.y; rp[t * 4 + 2] = r4.z; rp[t * 4 + 3] = r4.w;
        __syncthreads();
        for (int e = t; e < 2048; e += 256) {
          int d = ei[2048 + e];
          int slot = atomicAdd(&rp[d], 1);
          esrc[slot] = ei[e];
          eatt[slot] = ((const float4*)eattr)[e];
        }
      }
      return;
    }
    // ---- bx==37: root staging, j=960+k (r9-verified layout) ----
    int l = blockIdx.y;
    for (int idx = t; idx < 36864; idx += 256) {
      float vv = root_w[(size_t)l * 36864 + idx];
      int k = idx / 192, o = idx - k * 192;
      int j = 960 + k;
      Btl[(size_t)l * 221184 + ((size_t)(j >> 3) * 192 + o) * 8 + (j & 7)] = (_Float16)vv;
    }
    return;
  }
  // ---- worker (r10-verbatim pipeline): wave=256 cols, 1KB gll16 requests, 8-buf counted vmcnt ----
  int w = t >> 6, lane = t & 63;
  int l = blockIdx.y;
  int wcol = blockIdx.x * 1024 + w * 256;
  const float* W2l = nn2_w + (size_t)l * 7077888;
  char* ldsbase = (char*)smem + w * 32768;
  f32x4 nb4 = *(const f32x4*)(nn2_b + (size_t)l * 36864 + wcol + 4 * lane);

#define ISSUE(tile)                                                             \
  {                                                                             \
    _Pragma("unroll")                                                           \
    for (int r = 0; r < 4; ++r) {                                               \
      int row = (tile) * 4 + r;                                                 \
      gll16((const char*)(W2l + (size_t)row * 36864 + wcol) + lane * 16,        \
            ldsbase + ((tile) & 7) * 4096 + r * 1024 + lane * 16);              \
    }                                                                           \
  }

  ISSUE(0); ISSUE(1); ISSUE(2); ISSUE(3); ISSUE(4); ISSUE(5); ISSUE(6);
  if (t < 192) {
    float a0 = 0.f, a1 = 0.f, a2 = 0.f, a3 = 0.f, a4 = 0.f;
    const float* nw = nn1_w + (size_t)l * 36864 + t;
    for (int k = 0; k < 192; ++k) {
      float nv = nw[(size_t)k * 192];
      a0 += eenc_w[k] * nv;
      a1 += eenc_w[192 + k] * nv;
      a2 += eenc_w[384 + k] * nv;
      a3 += eenc_w[576 + k] * nv;
      a4 += eenc_b[k] * nv;
    }
    smem[32768 + t] = a0; smem[32960 + t] = a1; smem[33152 + t] = a2;
    smem[33344 + t] = a3; smem[33536 + t] = a4 + nn1_b[l * 192 + t];
  }
  __syncthreads();

  f32x4 a[5] = {};
  const float* Ms = smem + 32768;
  for (int tile = 0; tile < 48; ++tile) {
    if (tile < 41) ISSUE(tile + 7);
    if (tile < 41)       asm volatile("s_waitcnt vmcnt(28)" ::: "memory");
    else if (tile == 41) asm volatile("s_waitcnt vmcnt(24)" ::: "memory");
    else if (tile == 42) asm volatile("s_waitcnt vmcnt(20)" ::: "memory");
    else if (tile == 43) asm volatile("s_waitcnt vmcnt(16)" ::: "memory");
    else if (tile == 44) asm volatile("s_waitcnt vmcnt(12)" ::: "memory");
    else if (tile == 45) asm volatile("s_waitcnt vmcnt(8)" ::: "memory");
    else if (tile == 46) asm volatile("s_waitcnt vmcnt(4)" ::: "memory");
    else                 asm volatile("s_waitcnt vmcnt(0)" ::: "memory");
    const float* wb = (const float*)(ldsbase) + (tile & 7) * 1024;
    const float* Mt = Ms + tile * 4;
#pragma unroll
    for (int r = 0; r < 4; ++r) {
      f32x4 wv = *(const f32x4*)(wb + r * 256 + 4 * lane);
#pragma unroll
      for (int c = 0; c < 5; ++c) a[c] += Mt[c * 192 + r] * wv;
    }
  }
#undef ISSUE
  a[4] += nb4;
  _Float16* base = Btl + (size_t)l * 221184;
#pragma unroll
  for (int cc = 0; cc < 4; ++cc) {
    int col = wcol + 4 * lane + cc;
    int i = col / 192, o = col - i * 192;
#pragma unroll
    for (int c = 0; c < 5; ++c) {
      int j = c * 192 + i;
      base[((size_t)(j >> 3) * 192 + o) * 8 + (j & 7)] = (_Float16)a[c][cc];
    }
  }
}

// ---- k_lyr: fused {CSR gather -> A | GEMM [8x1152]@[1152x192] | bias+res+LN+relu | z/out} ----
// 128 blocks x 8 dst rows. A = [G_0..G_4 | z_root], chunk-major; A rows 8..15 zeroed.
__global__ __launch_bounds__(256)
void k_lyr(const _Float16* __restrict__ z16in, const _Float16* __restrict__ B2l,
           const int* __restrict__ rowptr, const int* __restrict__ esrc,
           const float4* __restrict__ eatt4, const float* __restrict__ hp,
           const float* __restrict__ cbv, const float* __restrict__ gg,
           const float* __restrict__ bb, float* __restrict__ ho,
           _Float16* __restrict__ z16out, const float* __restrict__ out_w,
           const float* __restrict__ out_b, float* __restrict__ outp, int l) {
  __shared__ __align__(16) _Float16 A_lds[18432];  // 144 ck x 16 rows x 8
  __shared__ float2 lnred[4][8];
  __shared__ float2 outred[4][8];
  int t = threadIdx.x, w = t >> 6, lane = t & 63, l15 = lane & 15, q4 = lane >> 4;
  int n0 = blockIdx.x * 8;
  // zero A rows 8..15 (144 ck x 8 rows x 8 halfs = 1152 uint4)
  for (int i = t; i < 1152; i += 256) {
    int ck = i >> 3, sub = i & 7;
    *(uint4*)(A_lds + ck * 128 + 64 + sub * 8) = make_uint4(0, 0, 0, 0);
  }
  // gather: wave w owns rows {2w, 2w+1}
#pragma unroll
  for (int rr2 = 0; rr2 < 2; ++rr2) {
    int row = w * 2 + rr2, n = n0 + row;
    float g[5][3] = {};
    int beg = rowptr[n], end = rowptr[n + 1];
    for (int idx = beg; idx < end; ++idx) {
      int s = esrc[idx];
      float4 u = eatt4[idx];
#pragma unroll
      for (int m = 0; m < 3; ++m) {
        float zv = (float)z16in[(size_t)s * 192 + lane + 64 * m];
        g[0][m] += u.x * zv; g[1][m] += u.y * zv;
        g[2][m] += u.z * zv; g[3][m] += u.w * zv;
        g[4][m] += zv;
      }
    }
#pragma unroll
    for (int m = 0; m < 3; ++m) {
      int i = lane + 64 * m;
#pragma unroll
      for (int c = 0; c < 5; ++c) {
        int j = c * 192 + i;
        A_lds[((j >> 3) * 16 + row) * 8 + (j & 7)] = (_Float16)g[c][m];
      }
      int j = 960 + i;
      A_lds[((j >> 3) * 16 + row) * 8 + (j & 7)] = z16in[(size_t)n * 192 + i];
    }
  }
  __syncthreads();
  // GEMM: wave w -> cols w*48 + nt*16 + l15, K=1152
  f32x4 acc[3] = {};
#pragma unroll 4
  for (int ks = 0; ks < 36; ++ks) {
    half8 av = *(const half8*)(A_lds + (((ks * 4 + q4) * 16) + l15) * 8);
#pragma unroll
    for (int nt = 0; nt < 3; ++nt) {
      half8 bv = *(const half8*)(B2l + (((size_t)(ks * 4 + q4)) * 192 + w * 48 + nt * 16 + l15) * 8);
      acc[nt] = __builtin_amdgcn_mfma_f32_16x16x32_f16(av, bv, acc[nt], 0, 0, 0);
    }
  }
  // epilogue: valid rows = q4<2 (C rows 0..7)
  float v[3][4];
  float p1[4] = {0.f, 0.f, 0.f, 0.f}, p2[4] = {0.f, 0.f, 0.f, 0.f};
  bool valid = (q4 < 2);
#pragma unroll
  for (int r = 0; r < 4; ++r) {
    int row = q4 * 4 + r;
    int n = n0 + (row & 7);
#pragma unroll
    for (int nt = 0; nt < 3; ++nt) {
      int col = w * 48 + nt * 16 + l15;
      float xv = acc[nt][r] + cbv[col];
      if (l > 0) xv += hp[(size_t)n * 192 + col];
      if (l < 3 && valid) ho[(size_t)n * 192 + col] = xv;
      v[nt][r] = xv;
      p1[r] += xv; p2[r] += xv * xv;
    }
  }
#pragma unroll
  for (int off = 1; off < 16; off <<= 1)
#pragma unroll
    for (int r = 0; r < 4; ++r) {
      p1[r] += __shfl_xor(p1[r], off);
      p2[r] += __shfl_xor(p2[r], off);
    }
  if (l15 == 0 && valid)
#pragma unroll
    for (int r = 0; r < 4; ++r) lnred[w][q4 * 4 + r] = make_float2(p1[r], p2[r]);
  __syncthreads();
  float po0[4] = {0.f, 0.f, 0.f, 0.f}, po1[4] = {0.f, 0.f, 0.f, 0.f};
  if (valid) {
#pragma unroll
    for (int r = 0; r < 4; ++r) {
      int row = q4 * 4 + r, n = n0 + row;
      float s1 = 0.f, s2 = 0.f;
#pragma unroll
      for (int ww = 0; ww < 4; ++ww) { float2 pr = lnred[ww][row]; s1 += pr.x; s2 += pr.y; }
      float mu = s1 * (1.f / 192.f);
      float var = s2 * (1.f / 192.f) - mu * mu;
      float rcp = rsqrtf(var + 1e-5f);
#pragma unroll
      for (int nt = 0; nt < 3; ++nt) {
        int col = w * 48 + nt * 16 + l15;
        float zval = fmaxf((v[nt][r] - mu) * rcp * gg[col] + bb[col], 0.f);
        if (l < 3) {
          z16out[(size_t)n * 192 + col] = (_Float16)zval;
        } else {
          po0[r] += zval * out_w[col * 2];
          po1[r] += zval * out_w[col * 2 + 1];
        }
      }
    }
  }
  if (l == 3) {
#pragma unroll
    for (int off = 1; off < 16; off <<= 1)
#pragma unroll
      for (int r = 0; r < 4; ++r) {
        po0[r] += __shfl_xor(po0[r], off);
        po1[r] += __shfl_xor(po1[r], off);
      }
    if (l15 == 0 && valid)
#pragma unroll
      for (int r = 0; r < 4; ++r) outred[w][q4 * 4 + r] = make_float2(po0[r], po1[r]);
    __syncthreads();
    if (t < 16) {
      int row = t >> 1, c = t & 1;
      float s = 0.f;
#pragma unroll
      for (int ww = 0; ww < 4; ++ww) { float2 pr = outred[ww][row]; s += (c == 0) ? pr.x : pr.y; }
      outp[(n0 + row) * 2 + c] = s + out_b[c];
    }
  }
}

// ---------------- launch ----------------
extern "C" void kernel_launch(void* const* d_in, const int* in_sizes, int n_in,
                              void* d_out, int out_size, void* d_ws, size_t ws_size,
                              hipStream_t stream) {
  const float* x      = (const float*)d_in[0];
  const int*   ei     = (const int*)  d_in[1];
  const float* eattr  = (const float*)d_in[2];
  const float* cheb_w = (const float*)d_in[4];
  const float* cheb_b = (const float*)d_in[5];
  const float* eenc_w = (const float*)d_in[6];
  const float* eenc_b = (const float*)d_in[7];
  const float* nn1_w  = (const float*)d_in[8];
  const float* nn1_b  = (const float*)d_in[9];
  const float* nn2_w  = (const float*)d_in[10];
  const float* nn2_b  = (const float*)d_in[11];
  const float* root_w = (const float*)d_in[12];
  const float* conv_b = (const float*)d_in[13];
  const float* ln_g   = (const float*)d_in[14];
  const float* ln_bb  = (const float*)d_in[15];
  const float* out_w  = (const float*)d_in[16];
  const float* out_b  = (const float*)d_in[17];
  float* outp = (float*)d_out;
  (void)in_sizes; (void)n_in; (void)out_size; (void)ws_size;

  char* p = (char*)d_ws;
  _Float16* Btl = (_Float16*)p; p += (size_t)4 * 221184 * 2;   // 1.77 MB
  float* hA     = (float*)p;    p += 196608 * 4;
  float* hB     = (float*)p;    p += 196608 * 4;
  _Float16* z0  = (_Float16*)p; p += 196608 * 2;
  _Float16* zA  = (_Float16*)p; p += 196608 * 2;
  _Float16* zB  = (_Float16*)p; p += 196608 * 2;
  int* rowptr   = (int*)p;      p += 1056 * 4;
  int* esrc     = (int*)p;      p += 2048 * 4;
  float4* eatt  = (float4*)p;   p += 2048 * 16;

  k_pb<<<dim3(38, 4), 256, 0, stream>>>(nn2_w, nn2_b, eenc_w, eenc_b, nn1_w, nn1_b,
                                        root_w, Btl, x, ei, eattr, cheb_w, cheb_b,
                                        z0, rowptr, esrc, eatt);

  const _Float16* zin[4] = {z0, zA, zB, zA};
  _Float16* zout[4] = {zA, zB, zA, zA};       // zout[3] unused (l==3 guards)
  float* hout[4] = {hA, hB, hA, hA};          // hout[3] unused
  const float* hres[4] = {hA, hA, hB, hA};    // hres[0] unused
  for (int l = 0; l < 4; ++l) {
    k_lyr<<<128, 256, 0, stream>>>(zin[l], Btl + (size_t)l * 221184, rowptr, esrc,
                                   eatt, hres[l], conv_b + (size_t)l * 192,
                                   ln_g + (size_t)((l == 3) ? 0 : (l + 1)) * 192,
                                   ln_bb + (size_t)((l == 3) ? 0 : (l + 1)) * 192,
                                   hout[l], zout[l], out_w, out_b, outp, l);
  }
}

// Round 12
// 345.115 us; speedup vs baseline: 1.1676x; 1.1676x over previous
//
#include <hip/hip_runtime.h>
#include <stdint.h>

typedef _Float16 half8 __attribute__((ext_vector_type(8)));
typedef float f32x4 __attribute__((ext_vector_type(4)));

// ---- k_pb: Ppart[kq][l][c][:] = partial M @ W2, streaming 12KB-contiguous row bursts ----
// grid (13,4,4): bx<12 workers (3072-col slice, layer by, k-quarter bz).
// bx==12 riders: (y0,z0) cheb->Tx; (y1,z0) CSR; (y2,z0) root l0,l1; (y3,z0) root l2,l3.
__global__ __launch_bounds__(256)
void k_pb(const float* __restrict__ nn2_w, const float* __restrict__ eenc_w,
          const float* __restrict__ eenc_b, const float* __restrict__ nn1_w,
          const float* __restrict__ nn1_b, const float* __restrict__ root_w,
          float* __restrict__ Ppart, _Float16* __restrict__ Btl,
          const float* __restrict__ x, const int* __restrict__ ei,
          float* __restrict__ Tx, int* __restrict__ rowptr, int* __restrict__ eord) {
  __shared__ __align__(16) float smem[8192];  // riders: 32KB; workers: M in [0,960)
  int t = threadIdx.x;
  if (blockIdx.x == 12) {
    if (blockIdx.z != 0) return;
    if (blockIdx.y == 0) {
      // ---- Chebyshev chain (r5/r7/r8/r10-verified), Tx to global ----
      float* cur = smem;
      float* yv = smem + 4096;
      float* deg = yv;
      for (int i = t; i < 1024; i += 256) deg[i] = 0.f;
      __syncthreads();
      for (int e = t; e < 2048; e += 256) atomicAdd(&deg[ei[e]], 1.f);
      __syncthreads();
      float wn[8];
#pragma unroll
      for (int i = 0; i < 8; ++i) {
        int e = t + 256 * i;
        int s = ei[e], d = ei[2048 + e];
        float ds = deg[s], dd = deg[d];
        float a = ds > 0.f ? 1.f / sqrtf(fmaxf(ds, 1.f)) : 0.f;
        float bb = dd > 0.f ? 1.f / sqrtf(fmaxf(dd, 1.f)) : 0.f;
        wn[i] = -a * bb;
      }
      __syncthreads();
      float4 prev[4];
#pragma unroll
      for (int q = 0; q < 4; ++q) {
        int i = t + 256 * q;
        float4 xv = ((const float4*)x)[i];
        ((float4*)cur)[i] = xv;
        ((float4*)Tx)[i] = xv;
      }
      __syncthreads();
      for (int rec = 0; rec < 4; ++rec) {
        for (int i = t; i < 4096; i += 256) yv[i] = 0.f;
        __syncthreads();
#pragma unroll
        for (int i = 0; i < 8; ++i) {
          int e = t + 256 * i;
          int s = ei[e], d = ei[2048 + e];
          float wv = wn[i];
#pragma unroll
          for (int c = 0; c < 4; ++c) atomicAdd(&yv[d * 4 + c], wv * cur[s * 4 + c]);
        }
        __syncthreads();
        float a = rec ? 2.f : 1.f;
#pragma unroll
        for (int q = 0; q < 4; ++q) {
          int i = t + 256 * q;
          float4 y4 = ((float4*)yv)[i];
          float4 c4 = ((float4*)cur)[i];
          float4 n4;
          n4.x = a * y4.x - (rec ? prev[q].x : 0.f);
          n4.y = a * y4.y - (rec ? prev[q].y : 0.f);
          n4.z = a * y4.z - (rec ? prev[q].z : 0.f);
          n4.w = a * y4.w - (rec ? prev[q].w : 0.f);
          prev[q] = c4;
          ((float4*)cur)[i] = n4;
          ((float4*)(Tx + (rec + 1) * 4096))[i] = n4;
        }
        __syncthreads();
      }
    } else if (blockIdx.y == 1) {
      // ---- CSR by dst (verified) ----
      int* cnt = (int*)smem;
      int* rp  = (int*)smem + 1024;
      int* wtot = (int*)smem + 2048;
      int lane = t & 63, wv = t >> 6;
      for (int i = t; i < 1024; i += 256) cnt[i] = 0;
      __syncthreads();
      for (int e = t; e < 2048; e += 256) atomicAdd(&cnt[ei[2048 + e]], 1);
      __syncthreads();
      int c0 = cnt[t * 4], c1 = cnt[t * 4 + 1], c2 = cnt[t * 4 + 2], c3 = cnt[t * 4 + 3];
      int s = c0 + c1 + c2 + c3;
      int inc = s;
#pragma unroll
      for (int off = 1; off < 64; off <<= 1) {
        int u = __shfl_up(inc, off);
        if (lane >= off) inc += u;
      }
      if (lane == 63) wtot[wv] = inc;
      __syncthreads();
      int woff = 0;
#pragma unroll
      for (int j = 0; j < 4; ++j) if (j < wv) woff += wtot[j];
      int excl = woff + inc - s;
      int4 r4; r4.x = excl; r4.y = excl + c0; r4.z = excl + c0 + c1; r4.w = excl + c0 + c1 + c2;
      *(int4*)(rowptr + t * 4) = r4;
      if (t == 0) rowptr[1024] = 2048;
      rp[t * 4] = r4.x; rp[t * 4 + 1] = r4.y; rp[t * 4 + 2] = r4.z; rp[t * 4 + 3] = r4.w;
      __syncthreads();
      for (int e = t; e < 2048; e += 256) {
        int d = ei[2048 + e];
        int slot = atomicAdd(&rp[d], 1);
        eord[slot] = e;
      }
    } else {
      // ---- root staging: 2 layers per block ----
      int lbase = (blockIdx.y - 2) * 2;
#pragma unroll
      for (int rep = 0; rep < 2; ++rep) {
        int l = lbase + rep;
        for (int idx = t; idx < 36864; idx += 256) {
          float v = root_w[(size_t)l * 36864 + idx];
          int i = idx / 192, o = idx - i * 192;
          Btl[(size_t)l * 221184 + (i >> 3) * 9216 + (size_t)(960 + o) * 8 + (i & 7)] = (_Float16)v;
        }
      }
    }
    return;
  }
  // ---- worker: M in LDS (verified build), then 48 rows x 12KB contiguous bursts ----
  int l = blockIdx.y, kq = blockIdx.z;
  if (t < 192) {
    float a0 = 0.f, a1 = 0.f, a2 = 0.f, a3 = 0.f, a4 = 0.f;
    const float* nw = nn1_w + (size_t)l * 36864 + t;
    for (int k = 0; k < 192; ++k) {
      float nv = nw[(size_t)k * 192];
      a0 += eenc_w[k] * nv;
      a1 += eenc_w[192 + k] * nv;
      a2 += eenc_w[384 + k] * nv;
      a3 += eenc_w[576 + k] * nv;
      a4 += eenc_b[k] * nv;
    }
    smem[t] = a0; smem[192 + t] = a1; smem[384 + t] = a2;
    smem[576 + t] = a3; smem[768 + t] = a4 + nn1_b[l * 192 + t];
  }
  __syncthreads();
  const float* Wp = nn2_w + (size_t)l * 7077888 + (size_t)(kq * 48) * 36864
                    + blockIdx.x * 3072 + t * 4;
  const float* Ms = smem;
  int k0 = kq * 48;
  f32x4 acc0 = {}, acc1 = {}, acc2 = {}, acc3 = {}, acc4 = {};
  f32x4 acc0b = {}, acc1b = {}, acc2b = {}, acc3b = {}, acc4b = {};
  f32x4 acc0c = {}, acc1c = {}, acc2c = {}, acc3c = {}, acc4c = {};
#pragma unroll 4
  for (int r = 0; r < 48; ++r) {
    const float* rp = Wp + (size_t)r * 36864;
    f32x4 w0 = *(const f32x4*)(rp);
    f32x4 w1 = *(const f32x4*)(rp + 1024);
    f32x4 w2 = *(const f32x4*)(rp + 2048);
    int k = k0 + r;
    float m0 = Ms[k], m1 = Ms[192 + k], m2 = Ms[384 + k], m3 = Ms[576 + k], m4 = Ms[768 + k];
    acc0 += m0 * w0; acc0b += m0 * w1; acc0c += m0 * w2;
    acc1 += m1 * w0; acc1b += m1 * w1; acc1c += m1 * w2;
    acc2 += m2 * w0; acc2b += m2 * w1; acc2c += m2 * w2;
    acc3 += m3 * w0; acc3b += m3 * w1; acc3c += m3 * w2;
    acc4 += m4 * w0; acc4b += m4 * w1; acc4c += m4 * w2;
  }
  float* Pp = Ppart + ((size_t)(kq * 4 + l) * 5) * 36864 + blockIdx.x * 3072 + t * 4;
  *(f32x4*)(Pp) = acc0;               *(f32x4*)(Pp + 1024) = acc0b;        *(f32x4*)(Pp + 2048) = acc0c;
  *(f32x4*)(Pp + 36864) = acc1;       *(f32x4*)(Pp + 36864 + 1024) = acc1b; *(f32x4*)(Pp + 36864 + 2048) = acc1c;
  *(f32x4*)(Pp + 2 * 36864) = acc2;   *(f32x4*)(Pp + 2 * 36864 + 1024) = acc2b; *(f32x4*)(Pp + 2 * 36864 + 2048) = acc2c;
  *(f32x4*)(Pp + 3 * 36864) = acc3;   *(f32x4*)(Pp + 3 * 36864 + 1024) = acc3b; *(f32x4*)(Pp + 3 * 36864 + 2048) = acc3c;
  *(f32x4*)(Pp + 4 * 36864) = acc4;   *(f32x4*)(Pp + 4 * 36864 + 1024) = acc4b; *(f32x4*)(Pp + 4 * 36864 + 2048) = acc4c;
}

// ---- k_stage: B = f16(sum of 4 k-partials + bias), r10 Btl layout ----
__global__ __launch_bounds__(256)
void k_stage(const float* __restrict__ Ppart, const float* __restrict__ nn2_b,
             _Float16* __restrict__ Btl) {
  int t = threadIdx.x, l = blockIdx.y;
  _Float16* base = Btl + (size_t)l * 221184;
#pragma unroll
  for (int q = 0; q < 4; ++q) {
    int j = blockIdx.x * 1024 + q * 256 + t;
    float s0 = 0.f, s1 = 0.f, s2 = 0.f, s3 = 0.f, s4 = 0.f;
#pragma unroll
    for (int kq = 0; kq < 4; ++kq) {
      const float* Pp = Ppart + ((size_t)(kq * 4 + l) * 5) * 36864 + j;
      s0 += Pp[0];
      s1 += Pp[36864];
      s2 += Pp[2 * 36864];
      s3 += Pp[3 * 36864];
      s4 += Pp[4 * 36864];
    }
    s4 += nn2_b[(size_t)l * 36864 + j];
    int i = j / 192, o = j - i * 192;
    _Float16* B0 = base + (i >> 3) * 9216 + (i & 7);
    B0[(size_t)(0 * 192 + o) * 8] = (_Float16)s0;
    B0[(size_t)(1 * 192 + o) * 8] = (_Float16)s1;
    B0[(size_t)(2 * 192 + o) * 8] = (_Float16)s2;
    B0[(size_t)(3 * 192 + o) * 8] = (_Float16)s3;
    B0[(size_t)(4 * 192 + o) * 8] = (_Float16)s4;
  }
}

// ---- Y = z16 @ B (1024x1152, K=192); layer 0 builds its A-tile from Tx (r10-verbatim) ----
__global__ __launch_bounds__(256)
void k_y(const _Float16* __restrict__ z16, const _Float16* __restrict__ Btl,
         float* __restrict__ Y, const float* __restrict__ Tx,
         const float* __restrict__ cheb_w, const float* __restrict__ cheb_b, int layer) {
  __shared__ __align__(16) _Float16 Als[12288];
  int t = threadIdx.x;
  int w = t >> 6, lane = t & 63, l15 = lane & 15, q4 = lane >> 4;
  int e0 = blockIdx.x * 64, cb = blockIdx.y;
  if (layer == 0) {
#pragma unroll
    for (int it = 0; it < 6; ++it) {
      int u = it * 256 + t;
      int row = u & 63, ck = u >> 6;
      int n = e0 + row;
      float tv[5][4];
#pragma unroll
      for (int k = 0; k < 5; ++k) {
        float4 t4 = ((const float4*)(Tx + k * 4096))[n];
        tv[k][0] = t4.x; tv[k][1] = t4.y; tv[k][2] = t4.z; tv[k][3] = t4.w;
      }
      union { _Float16 h[8]; uint4 v; } u8;
#pragma unroll
      for (int j = 0; j < 8; ++j) {
        int o = ck * 8 + j;
        float acc = cheb_b[o];
#pragma unroll
        for (int k = 0; k < 5; ++k)
#pragma unroll
          for (int c = 0; c < 4; ++c)
            acc += tv[k][c] * cheb_w[(k * 4 + c) * 192 + o];
        u8.h[j] = (_Float16)acc;
      }
      *(uint4*)(Als + (size_t)u * 8) = u8.v;
    }
    __syncthreads();
  }
  const _Float16* Bt = Btl + (size_t)layer * 221184;
  const _Float16* ap = z16 + (((size_t)q4 * 1024) + e0 + w * 16 + l15) * 8;
  const _Float16* bp = Bt + (((size_t)q4 * 1152) + cb * 192 + l15) * 8;
  f32x4 acc[12] = {};
#pragma unroll
  for (int ks = 0; ks < 6; ++ks) {
    half8 av;
    if (layer == 0)
      av = *(const half8*)(Als + (((size_t)(ks * 4 + q4) * 64) + w * 16 + l15) * 8);
    else
      av = *(const half8*)(ap + (size_t)ks * 4 * 1024 * 8);
#pragma unroll
    for (int nt = 0; nt < 12; ++nt) {
      half8 bv = *(const half8*)(bp + (size_t)ks * 4 * 1152 * 8 + nt * 16 * 8);
      acc[nt] = __builtin_amdgcn_mfma_f32_16x16x32_f16(av, bv, acc[nt], 0, 0, 0);
    }
  }
#pragma unroll
  for (int nt = 0; nt < 12; ++nt) {
    int col = cb * 192 + nt * 16 + l15;
#pragma unroll
    for (int r = 0; r < 4; ++r) {
      int row = e0 + w * 16 + q4 * 4 + r;
      Y[(size_t)row * 1152 + col] = acc[nt][r];
    }
  }
}

// ---- gather by dst (CSR) + root + bias + residual + LN + relu (+ final for l==3) (r10-verbatim) ----
__global__ __launch_bounds__(256)
void k_gn(const int* __restrict__ ei, const float* __restrict__ eattr,
          const int* __restrict__ rowptr, const int* __restrict__ eord,
          const float* __restrict__ Y, const float* __restrict__ hp,
          const float* __restrict__ cbv, const float* __restrict__ gg,
          const float* __restrict__ bb, float* __restrict__ ho,
          _Float16* __restrict__ zo, const float* __restrict__ out_w,
          const float* __restrict__ out_b, float* __restrict__ outp, int l) {
  int t = threadIdx.x, w = t >> 6, lane = t & 63;
  int n = blockIdx.x * 4 + w;
  int o0 = lane, o1 = lane + 64, o2 = lane + 128;
  float v0 = 0.f, v1 = 0.f, v2 = 0.f;
  int beg = rowptr[n], end = rowptr[n + 1];
  for (int idx = beg; idx < end; ++idx) {
    int e = eord[idx];
    int s = ei[e];
    float4 u = ((const float4*)eattr)[e];
    const float* yr = Y + (size_t)s * 1152;
    v0 += yr[o0] * u.x + yr[192 + o0] * u.y + yr[384 + o0] * u.z + yr[576 + o0] * u.w + yr[768 + o0];
    v1 += yr[o1] * u.x + yr[192 + o1] * u.y + yr[384 + o1] * u.z + yr[576 + o1] * u.w + yr[768 + o1];
    v2 += yr[o2] * u.x + yr[192 + o2] * u.y + yr[384 + o2] * u.z + yr[576 + o2] * u.w + yr[768 + o2];
  }
  const float* yn = Y + (size_t)n * 1152 + 960;
  v0 += yn[o0] + cbv[o0]; v1 += yn[o1] + cbv[o1]; v2 += yn[o2] + cbv[o2];
  if (l > 0) {
    v0 += hp[n * 192 + o0]; v1 += hp[n * 192 + o1]; v2 += hp[n * 192 + o2];
  }
  if (l < 3) {
    ho[n * 192 + o0] = v0; ho[n * 192 + o1] = v1; ho[n * 192 + o2] = v2;
  }
  float s1 = v0 + v1 + v2, s2 = v0 * v0 + v1 * v1 + v2 * v2;
#pragma unroll
  for (int off = 32; off >= 1; off >>= 1) {
    s1 += __shfl_xor(s1, off);
    s2 += __shfl_xor(s2, off);
  }
  float mu = s1 * (1.f / 192.f);
  float var = s2 * (1.f / 192.f) - mu * mu;
  float rcp = rsqrtf(var + 1e-5f);
  float z0v = fmaxf((v0 - mu) * rcp * gg[o0] + bb[o0], 0.f);
  float z1v = fmaxf((v1 - mu) * rcp * gg[o1] + bb[o1], 0.f);
  float z2v = fmaxf((v2 - mu) * rcp * gg[o2] + bb[o2], 0.f);
  if (l < 3) {
    zo[((size_t)(o0 >> 3) * 1024 + n) * 8 + (o0 & 7)] = (_Float16)z0v;
    zo[((size_t)(o1 >> 3) * 1024 + n) * 8 + (o1 & 7)] = (_Float16)z1v;
    zo[((size_t)(o2 >> 3) * 1024 + n) * 8 + (o2 & 7)] = (_Float16)z2v;
  } else {
    float a0 = z0v * out_w[o0 * 2] + z1v * out_w[o1 * 2] + z2v * out_w[o2 * 2];
    float a1 = z0v * out_w[o0 * 2 + 1] + z1v * out_w[o1 * 2 + 1] + z2v * out_w[o2 * 2 + 1];
#pragma unroll
    for (int off = 32; off >= 1; off >>= 1) {
      a0 += __shfl_xor(a0, off);
      a1 += __shfl_xor(a1, off);
    }
    if (lane == 0) {
      outp[n * 2] = a0 + out_b[0];
      outp[n * 2 + 1] = a1 + out_b[1];
    }
  }
}

// ---------------- launch ----------------
extern "C" void kernel_launch(void* const* d_in, const int* in_sizes, int n_in,
                              void* d_out, int out_size, void* d_ws, size_t ws_size,
                              hipStream_t stream) {
  const float* x      = (const float*)d_in[0];
  const int*   ei     = (const int*)  d_in[1];
  const float* eattr  = (const float*)d_in[2];
  const float* cheb_w = (const float*)d_in[4];
  const float* cheb_b = (const float*)d_in[5];
  const float* eenc_w = (const float*)d_in[6];
  const float* eenc_b = (const float*)d_in[7];
  const float* nn1_w  = (const float*)d_in[8];
  const float* nn1_b  = (const float*)d_in[9];
  const float* nn2_w  = (const float*)d_in[10];
  const float* nn2_b  = (const float*)d_in[11];
  const float* root_w = (const float*)d_in[12];
  const float* conv_b = (const float*)d_in[13];
  const float* ln_g   = (const float*)d_in[14];
  const float* ln_bb  = (const float*)d_in[15];
  const float* out_w  = (const float*)d_in[16];
  const float* out_b  = (const float*)d_in[17];
  float* outp = (float*)d_out;
  (void)in_sizes; (void)n_in; (void)out_size; (void)ws_size;

  char* p = (char*)d_ws;
  _Float16* Btl = (_Float16*)p; p += (size_t)4 * 221184 * 2;          // 1.77 MB
  float* Ppart  = (float*)p;    p += (size_t)4 * 4 * 5 * 36864 * 4;   // 11.8 MB
  float* Tx     = (float*)p;    p += 5 * 4096 * 4;
  float* Y      = (float*)p;    p += (size_t)1024 * 1152 * 4;         // 4.7 MB
  float* hA     = (float*)p;    p += 196608 * 4;
  float* hB     = (float*)p;    p += 196608 * 4;
  _Float16* zA  = (_Float16*)p; p += 196608 * 2;
  _Float16* zB  = (_Float16*)p; p += 196608 * 2;
  int* rowptr   = (int*)p;      p += 1056 * 4;
  int* eord     = (int*)p;      p += 2048 * 4;

  k_pb<<<dim3(13, 4, 4), 256, 0, stream>>>(nn2_w, eenc_w, eenc_b, nn1_w, nn1_b,
                                           root_w, Ppart, Btl, x, ei, Tx, rowptr, eord);
  k_stage<<<dim3(36, 4), 256, 0, stream>>>(Ppart, nn2_b, Btl);

  const _Float16* zin[4] = {zA, zA, zB, zA};  // zin[0] unused (layer 0 builds A from Tx)
  _Float16* zout[4] = {zA, zB, zA, zA};       // zout[3] unused
  float* hout[4] = {hA, hB, hA, hA};          // hout[3] unused
  const float* hres[4] = {hA, hA, hB, hA};    // hres[0] unused
  for (int l = 0; l < 4; ++l) {
    k_y<<<dim3(16, 6), 256, 0, stream>>>(zin[l], Btl, Y, Tx, cheb_w, cheb_b, l);
    k_gn<<<256, 256, 0, stream>>>(ei, eattr, rowptr, eord, Y, hres[l],
                                  conv_b + (size_t)l * 192,
                                  ln_g + (size_t)((l == 3) ? 0 : (l + 1)) * 192,
                                  ln_bb + (size_t)((l == 3) ? 0 : (l + 1)) * 192,
                                  hout[l], zout[l], out_w, out_b, outp, l);
  }
}